// Round 1
// baseline (227.258 us; speedup 1.0000x reference)
//
#include <hip/hip_runtime.h>
#include <hip/hip_bf16.h>
#include <math.h>

#define NODES 128
#define KMIX  8
#define NSAMP 4096
#define STOT  8192            // X and noise stacked
#define ZPAIR 8128            // 128*127/2
#define ZSPLIT 2
#define ZHALF (ZPAIR / ZSPLIT)   // 4064
#define SPB   64              // samples per block (main kernel)
#define PADF  131             // padded feature row (floats): 3*lane mod 32 -> 2-way (free)

typedef float f32x4 __attribute__((ext_vector_type(4)));

// ---------------- ws layout (in floats) ----------------
#define OF_FC  ((size_t)0)
#define OF_FS  (OF_FC + (size_t)STOT * NODES)           // 1048576
#define OF_TT  (OF_FS + (size_t)STOT * NODES)           // 2097152
#define OF_PR  (OF_TT + (size_t)ZPAIR * 16)             // 2227200
#define OF_LP  (OF_PR + (size_t)ZPAIR)                  // 2235328
#define OF_PT  (OF_LP + (size_t)2 * STOT * KMIX)        // 2366400
// total ~ 2366432 floats ~ 9.5 MB

// ---------------------------------------------------------------------------
// prep: per-node sincos features + theta transpose + pair index table
// ---------------------------------------------------------------------------
__global__ void prep_kernel(const float* __restrict__ X,
                            const float* __restrict__ noise,
                            const float* __restrict__ theta,
                            float* __restrict__ Fc, float* __restrict__ Fs,
                            float* __restrict__ TT, unsigned* __restrict__ pairs) {
    int idx = blockIdx.x * blockDim.x + threadIdx.x;
    if (idx < STOT * NODES) {
        int s = idx >> 7;
        float v = (s < NSAMP) ? X[idx] : noise[idx - NSAMP * NODES];
        float sv, cv;
        __sincosf(v, &sv, &cv);
        Fc[idx] = cv;
        Fs[idx] = sv;
    }
    if (idx < ZPAIR) {
        // TT[z][0..7] = theta[k][0][z], TT[z][8..15] = theta[k][1][z]
        #pragma unroll
        for (int k = 0; k < KMIX; k++) {
            TT[idx * 16 + k]     = theta[(size_t)(k * 2 + 0) * ZPAIR + idx];
            TT[idx * 16 + 8 + k] = theta[(size_t)(k * 2 + 1) * ZPAIR + idx];
        }
        // pair (i,j) for this z, np.triu_indices(128, k=1) row-major order
        int rem = idx, i = 0;
        while (rem >= NODES - 1 - i) { rem -= NODES - 1 - i; i++; }
        int j = i + 1 + rem;
        pairs[idx] = (unsigned)i | ((unsigned)j << 16);
    }
}

// ---------------------------------------------------------------------------
// main: lp_part[zs][s][k] = sum over z-half of theta0*cos(d) + theta1*sin(d)
// grid: 256 blocks (128 sample-blocks x 2 z-splits), 256 threads
// ---------------------------------------------------------------------------
__global__ __launch_bounds__(256, 2) void main_kernel(
        const float* __restrict__ Fc, const float* __restrict__ Fs,
        const float* __restrict__ TT, const unsigned* __restrict__ pairs,
        float* __restrict__ lp_part) {
    __shared__ float Lc[SPB][PADF];
    __shared__ float Ls[SPB][PADF];

    const int t = threadIdx.x;
    const int sb = blockIdx.x >> 1;       // sample block 0..127
    const int zs = blockIdx.x & 1;        // z split
    const int sbase = sb * SPB;
    const int lane = t & 63;

    // cooperative feature stage: thread t -> row t>>2, 32-col quarter (t&3)
    {
        int r = t >> 2;
        int c0 = (t & 3) << 5;
        const float* gc = Fc + (size_t)(sbase + r) * NODES + c0;
        const float* gs = Fs + (size_t)(sbase + r) * NODES + c0;
        #pragma unroll
        for (int c = 0; c < 32; c += 4) {
            f32x4 vc = *(const f32x4*)(gc + c);
            f32x4 vs = *(const f32x4*)(gs + c);
            #pragma unroll
            for (int q = 0; q < 4; q++) {
                Lc[r][c0 + c + q] = vc[q];
                Ls[r][c0 + c + q] = vs[q];
            }
        }
    }
    __syncthreads();

    // wave-uniform z index -> theta/pair loads become scalar (s_load)
    const int swv = __builtin_amdgcn_readfirstlane(t >> 6);   // wave id 0..3
    const int zbase = zs * ZHALF;
    const float* __restrict__ TTb = TT + (size_t)zbase * 16;
    const unsigned* __restrict__ prb = pairs + zbase;

    float lp[KMIX];
    #pragma unroll
    for (int k = 0; k < KMIX; k++) lp[k] = 0.0f;

    #pragma unroll 2
    for (int it = 0; it < (ZHALF >> 2); ++it) {
        const int zz = swv + (it << 2);           // scalar
        const unsigned pr = prb[zz];              // scalar load
        const int i = (int)(pr & 0xffffu);
        const int j = (int)(pr >> 16);
        const float ci = Lc[lane][i], si = Ls[lane][i];
        const float cj = Lc[lane][j], sj = Ls[lane][j];
        const float cosd = fmaf(ci, cj, si * sj);
        const float sind = fmaf(si, cj, -(ci * sj));
        const float* tt = TTb + zz * 16;          // scalar base -> s_load row
        #pragma unroll
        for (int k = 0; k < KMIX; k++) {
            lp[k] = fmaf(tt[k], cosd, fmaf(tt[8 + k], sind, lp[k]));
        }
    }

    // cross-wave reduction (reuse Lc storage)
    __syncthreads();
    float* red = &Lc[0][0];                       // 4*64*8 = 2048 floats
    #pragma unroll
    for (int k = 0; k < KMIX; k++) red[((t >> 6) * 64 + lane) * KMIX + k] = lp[k];
    __syncthreads();

    // 256 threads -> 512 (sample,k) slots: each thread handles 2
    #pragma unroll
    for (int q = 0; q < 2; q++) {
        int idx = t * 2 + q;                      // 0..511
        int sl = idx >> 3;                        // sample 0..63
        int k = idx & 7;
        float v = red[(0 * 64 + sl) * KMIX + k] + red[(1 * 64 + sl) * KMIX + k]
                + red[(2 * 64 + sl) * KMIX + k] + red[(3 * 64 + sl) * KMIX + k];
        lp_part[((size_t)zs * STOT + sbase + sl) * KMIX + k] = v;
    }
}

// ---------------------------------------------------------------------------
// reduce: logsumexp over k, softplus terms, per-block partial sums
// ---------------------------------------------------------------------------
__device__ __forceinline__ float softplusf(float x) {
    return fmaxf(x, 0.0f) + log1pf(expf(-fabsf(x)));
}

__global__ void reduce_kernel(const float* __restrict__ lp_part,
                              const float* __restrict__ logc,
                              float* __restrict__ partials) {
    const int t = threadIdx.x;
    const int s = blockIdx.x * 256 + t;

    float v[KMIX];
    #pragma unroll
    for (int k = 0; k < KMIX; k++)
        v[k] = lp_part[(size_t)s * KMIX + k]
             + lp_part[(size_t)(STOT + s) * KMIX + k] + logc[k];

    float mx = v[0];
    #pragma unroll
    for (int k = 1; k < KMIX; k++) mx = fmaxf(mx, v[k]);
    float sum = 0.0f;
    #pragma unroll
    for (int k = 0; k < KMIX; k++) sum += expf(v[k] - mx);
    const float lp = mx + logf(sum);

    // n == m -> logN == logM: term1 = -softplus(-lp), term2 = -softplus(lp)
    const float term = (s < NSAMP) ? -softplusf(-lp) : -softplusf(lp);

    // block reduce (4 waves)
    float bsum = term;
    #pragma unroll
    for (int off = 32; off; off >>= 1) bsum += __shfl_down(bsum, off);
    __shared__ float wsum[4];
    if ((t & 63) == 0) wsum[t >> 6] = bsum;
    __syncthreads();
    if (t == 0) partials[blockIdx.x] = wsum[0] + wsum[1] + wsum[2] + wsum[3];
}

__global__ void final_kernel(const float* __restrict__ partials,
                             float* __restrict__ out) {
    const int t = threadIdx.x;
    float v = (t < 32) ? partials[t] : 0.0f;
    #pragma unroll
    for (int off = 32; off; off >>= 1) v += __shfl_down(v, off);
    if (t == 0) out[0] = v * (1.0f / (float)NSAMP);
}

// ---------------------------------------------------------------------------
extern "C" void kernel_launch(void* const* d_in, const int* in_sizes, int n_in,
                              void* d_out, int out_size, void* d_ws, size_t ws_size,
                              hipStream_t stream) {
    (void)in_sizes; (void)n_in; (void)out_size; (void)ws_size;
    const float* X     = (const float*)d_in[0];
    const float* noise = (const float*)d_in[1];
    const float* theta = (const float*)d_in[2];
    const float* logc  = (const float*)d_in[3];
    float* out = (float*)d_out;
    float* ws = (float*)d_ws;

    float*    Fc      = ws + OF_FC;
    float*    Fs      = ws + OF_FS;
    float*    TT      = ws + OF_TT;
    unsigned* pairs   = (unsigned*)(ws + OF_PR);
    float*    lp_part = ws + OF_LP;
    float*    parts   = ws + OF_PT;

    prep_kernel<<<(STOT * NODES + 255) / 256, 256, 0, stream>>>(
        X, noise, theta, Fc, Fs, TT, pairs);
    main_kernel<<<128 * ZSPLIT, 256, 0, stream>>>(Fc, Fs, TT, pairs, lp_part);
    reduce_kernel<<<STOT / 256, 256, 0, stream>>>(lp_part, logc, parts);
    final_kernel<<<1, 64, 0, stream>>>(parts, out);
}

// Round 2
// 30.813 us; speedup vs baseline: 7.3753x; 7.3753x over previous
//
#include <hip/hip_runtime.h>
#include <hip/hip_bf16.h>
#include <math.h>

#define NODES 128
#define KMIX  8
#define NSAMP 4096
#define STOT  8192            // X and noise stacked
#define ZPAIR 8128            // 128*127/2
#define FDIM  256             // [cos | sin] feature dim

using bf16x8 = __attribute__((ext_vector_type(8))) short;
using f32x4  = __attribute__((ext_vector_type(4))) float;

// ---------------- ws layout (in float slots) ----------------
#define OF_F   ((size_t)0)                          // bf16 F[8192][256]   -> 1048576 f32 slots
#define OF_M   (OF_F + (size_t)STOT * FDIM / 2)     // bf16 M[8][256][256] -> 262144
#define OF_LP4 (OF_M + (size_t)KMIX * FDIM * FDIM / 2)  // f32 [4][8][8192] -> 262144
#define OF_PT  (OF_LP4 + (size_t)4 * KMIX * STOT)   // f32 [32]
// total ~1.57M floats ~ 6.3 MB

__device__ __forceinline__ float bf2f(short u) {
    union { unsigned u32; float f; } cv;
    cv.u32 = ((unsigned)(unsigned short)u) << 16;
    return cv.f;
}
__device__ __forceinline__ short f2bf(float f) {
    union { float f; unsigned u32; } cv; cv.f = f;
    unsigned r = cv.u32 + 0x7fff + ((cv.u32 >> 16) & 1);   // round-nearest-even
    return (short)(r >> 16);
}
__device__ __forceinline__ float softplusf(float x) {
    return fmaxf(x, 0.0f) + log1pf(expf(-fabsf(x)));
}

// ---------------------------------------------------------------------------
// prep: per-node sincos features -> bf16 F[s][0..127]=cos, F[s][128..255]=sin
// ---------------------------------------------------------------------------
__global__ void prep_feat(const float* __restrict__ X, const float* __restrict__ noise,
                          short* __restrict__ F) {
    int idx = blockIdx.x * 256 + threadIdx.x;        // 0 .. STOT*NODES-1
    int s = idx >> 7, i = idx & 127;
    float v = (s < NSAMP) ? X[idx] : noise[idx - NSAMP * NODES];
    float sv, cv;
    __sincosf(v, &sv, &cv);
    F[(size_t)s * FDIM + i]       = f2bf(cv);
    F[(size_t)s * FDIM + 128 + i] = f2bf(sv);
}

// ---------------------------------------------------------------------------
// build_M: M_k[i][j] such that lp[k][s] = sum_{i,j} F[s,i] M_k[i,j] F[s,j]
//   pair (a<b), z=z(a,b):  M[a][b]=t0  M[128+a][128+b]=t0
//                          M[128+a][b]=t1  M[a][128+b]=-t1   (else 0)
// ---------------------------------------------------------------------------
__global__ void build_M(const float* __restrict__ theta, short* __restrict__ M) {
    int idx = blockIdx.x * 256 + threadIdx.x;        // 0 .. KMIX*256*256-1
    int j = idx & 255, i = (idx >> 8) & 255, k = idx >> 16;
    int a = i & 127, b = j & 127;
    float val = 0.0f;
    if (a < b) {
        int z = a * 127 - (a * (a - 1)) / 2 + (b - a - 1);
        int hi = i >> 7, hj = j >> 7;
        float t0 = theta[(size_t)(k * 2 + 0) * ZPAIR + z];
        float t1 = theta[(size_t)(k * 2 + 1) * ZPAIR + z];
        val = (hi == hj) ? t0 : (hi ? t1 : -t1);
    }
    M[idx] = f2bf(val);
}

// ---------------------------------------------------------------------------
// fused GEMM: per block (k, s-tile 128, i-half 128):
//   P[s,i] = sum_j F[s,j] * M_k[i,j]  (MFMA, K=256 in 4 chunks of 64)
//   lp4[part][k][s] += sum_i F[s,i] * P[s,i]  (fused epilogue)
// 4 waves in 2x2; XOR-swizzled LDS (src-side pre-swizzle + swizzled ds_read).
// ---------------------------------------------------------------------------
__global__ __launch_bounds__(256, 2) void gemm_fused(
        const short* __restrict__ F, const short* __restrict__ M,
        float* __restrict__ lp4) {
    __shared__ short Ft[2][128 * 64];
    __shared__ short Mt[2][128 * 64];

    const int bid = blockIdx.x;
    const int k   = bid >> 7;          // 128 blocks per k
    const int r_  = bid & 127;
    const int st  = r_ >> 1;           // sample tile 0..63
    const int ih  = r_ & 1;            // i half
    const int sbase = st * 128;
    const int ibase = ih * 128;

    const int t = threadIdx.x;
    const int wid = t >> 6, lane = t & 63;
    const int wm = wid >> 1, wn = wid & 1;

    const short* Mk = M + (size_t)k * FDIM * FDIM;

    // staging geometry: one global_load_lds(16B) covers 8 rows of 128B
    const int rg = lane >> 3;          // row within 8-row group (row&7 == rg)
    const int sc = (lane & 7) ^ rg;    // pre-swizzled source 16B-column

    f32x4 acc[4][4] = {};

    auto stage = [&](int buf, int c) {
        #pragma unroll
        for (int q = 0; q < 4; q++) {
            int g = wid * 4 + q;       // 8-row group 0..15
            const short* src = F + ((size_t)(sbase + g * 8 + rg)) * FDIM + c * 64 + sc * 8;
            __builtin_amdgcn_global_load_lds((const unsigned*)src,
                                             (unsigned*)&Ft[buf][g * 512], 16, 0, 0);
        }
        #pragma unroll
        for (int q = 0; q < 4; q++) {
            int g = wid * 4 + q;
            const short* src = Mk + ((size_t)(ibase + g * 8 + rg)) * FDIM + c * 64 + sc * 8;
            __builtin_amdgcn_global_load_lds((const unsigned*)src,
                                             (unsigned*)&Mt[buf][g * 512], 16, 0, 0);
        }
    };

    const int rlow = lane & 15, kq = lane >> 4;

    auto compute = [&](int buf) {
        bf16x8 afr[4][2], bfr[4][2];
        #pragma unroll
        for (int m = 0; m < 4; m++) {
            int row = wm * 64 + m * 16 + rlow;
            #pragma unroll
            for (int kk = 0; kk < 2; kk++) {
                int c16 = (kk * 4 + kq) ^ (row & 7);
                afr[m][kk] = *(const bf16x8*)&Ft[buf][row * 64 + c16 * 8];
            }
        }
        #pragma unroll
        for (int n = 0; n < 4; n++) {
            int row = wn * 64 + n * 16 + rlow;
            #pragma unroll
            for (int kk = 0; kk < 2; kk++) {
                int c16 = (kk * 4 + kq) ^ (row & 7);
                bfr[n][kk] = *(const bf16x8*)&Mt[buf][row * 64 + c16 * 8];
            }
        }
        #pragma unroll
        for (int m = 0; m < 4; m++)
            #pragma unroll
            for (int n = 0; n < 4; n++)
                #pragma unroll
                for (int kk = 0; kk < 2; kk++)
                    acc[m][n] = __builtin_amdgcn_mfma_f32_16x16x32_bf16(
                        afr[m][kk], bfr[n][kk], acc[m][n], 0, 0, 0);
    };

    stage(0, 0);
    #pragma unroll
    for (int c = 0; c < 4; c++) {
        if (c < 3) stage((c + 1) & 1, c + 1);
        __syncthreads();               // drains vmcnt -> current buf ready
        compute(c & 1);
        __syncthreads();               // reads retired before next overwrite
    }

    // ---- fused epilogue: psum[s] = sum_i F[s,i] * P[s,i] (this block's i-range)
    float psum[4][4];
    #pragma unroll
    for (int m = 0; m < 4; m++) {
        #pragma unroll
        for (int q = 0; q < 4; q++) {
            int srow = wm * 64 + m * 16 + kq * 4 + q;
            const short* fr = F + (size_t)(sbase + srow) * FDIM + ibase + wn * 64 + rlow;
            float p = 0.0f;
            #pragma unroll
            for (int n = 0; n < 4; n++)
                p += bf2f(fr[n * 16]) * acc[m][n][q];
            psum[m][q] = p;
        }
    }
    // reduce across the 16 lanes sharing each srow (low 4 lane bits)
    #pragma unroll
    for (int off = 1; off < 16; off <<= 1)
        #pragma unroll
        for (int m = 0; m < 4; m++)
            #pragma unroll
            for (int q = 0; q < 4; q++)
                psum[m][q] += __shfl_xor(psum[m][q], off, 64);

    if (rlow == 0) {
        int part = ih * 2 + wn;
        #pragma unroll
        for (int m = 0; m < 4; m++)
            #pragma unroll
            for (int q = 0; q < 4; q++) {
                int srow = wm * 64 + m * 16 + kq * 4 + q;
                lp4[((size_t)part * KMIX + k) * STOT + sbase + srow] = psum[m][q];
            }
    }
}

// ---------------------------------------------------------------------------
// reduce: sum 4 partials, logsumexp over k, softplus terms, per-block sums
// ---------------------------------------------------------------------------
__global__ void reduce_kernel(const float* __restrict__ lp4,
                              const float* __restrict__ logc,
                              float* __restrict__ partials) {
    const int t = threadIdx.x;
    const int s = blockIdx.x * 256 + t;

    float v[KMIX];
    #pragma unroll
    for (int k = 0; k < KMIX; k++) {
        v[k] = lp4[((size_t)0 * KMIX + k) * STOT + s]
             + lp4[((size_t)1 * KMIX + k) * STOT + s]
             + lp4[((size_t)2 * KMIX + k) * STOT + s]
             + lp4[((size_t)3 * KMIX + k) * STOT + s]
             + logc[k];
    }
    float mx = v[0];
    #pragma unroll
    for (int k = 1; k < KMIX; k++) mx = fmaxf(mx, v[k]);
    float sum = 0.0f;
    #pragma unroll
    for (int k = 0; k < KMIX; k++) sum += expf(v[k] - mx);
    const float lp = mx + logf(sum);

    // n == m -> term1 = -softplus(-lp_data), term2 = -softplus(lp_noise)
    const float term = (s < NSAMP) ? -softplusf(-lp) : -softplusf(lp);

    float bsum = term;
    #pragma unroll
    for (int off = 32; off; off >>= 1) bsum += __shfl_down(bsum, off);
    __shared__ float wsum[4];
    if ((t & 63) == 0) wsum[t >> 6] = bsum;
    __syncthreads();
    if (t == 0) partials[blockIdx.x] = wsum[0] + wsum[1] + wsum[2] + wsum[3];
}

__global__ void final_kernel(const float* __restrict__ partials,
                             float* __restrict__ out) {
    const int t = threadIdx.x;
    float v = (t < 32) ? partials[t] : 0.0f;
    #pragma unroll
    for (int off = 32; off; off >>= 1) v += __shfl_down(v, off);
    if (t == 0) out[0] = v * (1.0f / (float)NSAMP);
}

// ---------------------------------------------------------------------------
extern "C" void kernel_launch(void* const* d_in, const int* in_sizes, int n_in,
                              void* d_out, int out_size, void* d_ws, size_t ws_size,
                              hipStream_t stream) {
    (void)in_sizes; (void)n_in; (void)out_size; (void)ws_size;
    const float* X     = (const float*)d_in[0];
    const float* noise = (const float*)d_in[1];
    const float* theta = (const float*)d_in[2];
    const float* logc  = (const float*)d_in[3];
    float* out = (float*)d_out;
    float* ws  = (float*)d_ws;

    short* Fb   = (short*)(ws + OF_F);
    short* Mb   = (short*)(ws + OF_M);
    float* lp4  = ws + OF_LP4;
    float* parts = ws + OF_PT;

    prep_feat<<<STOT * NODES / 256, 256, 0, stream>>>(X, noise, Fb);
    build_M<<<KMIX * FDIM * FDIM / 256, 256, 0, stream>>>(theta, Mb);
    gemm_fused<<<KMIX * (STOT / 128) * 2, 256, 0, stream>>>(Fb, Mb, lp4);
    reduce_kernel<<<STOT / 256, 256, 0, stream>>>(lp4, logc, parts);
    final_kernel<<<1, 64, 0, stream>>>(parts, out);
}